// Round 1
// baseline (158.321 us; speedup 1.0000x reference)
//
#include <hip/hip_runtime.h>

// Masked embedding gather:
//   idx = x[i]; if (idx % 2 == 0) idx = 0;  out[i, :] = emb[idx, :]
// x: (8, 4096) int32, emb: (50257, 512) fp32, out: (8, 4096, 512) fp32.
//
// One 64-lane wave per token row. 512 floats/row = 128 float4 = 64 lanes x 2.
// Both the gather read (2 KiB contiguous per row) and the write are fully
// coalesced 16B/lane accesses.

#define EMB 512

__global__ __launch_bounds__(256) void embed_gather_kernel(
    const int* __restrict__ x,
    const float* __restrict__ emb,
    float* __restrict__ out,
    int n_tokens)
{
    const int gtid = blockIdx.x * blockDim.x + threadIdx.x;
    const int wave = gtid >> 6;          // global wave id = token id
    const int lane = threadIdx.x & 63;

    if (wave >= n_tokens) return;

    int idx = x[wave];                   // wave-uniform load
    if ((idx & 1) == 0) idx = 0;         // even token ids -> row 0 (ids are non-negative)

    const float4* __restrict__ src = (const float4*)(emb + (size_t)idx * EMB);
    float4* __restrict__ dst = (float4*)(out + (size_t)wave * EMB);

    // 128 float4 per row, 64 lanes -> 2 per lane
    float4 a = src[lane];
    float4 b = src[lane + 64];
    dst[lane] = a;
    dst[lane + 64] = b;
}

extern "C" void kernel_launch(void* const* d_in, const int* in_sizes, int n_in,
                              void* d_out, int out_size, void* d_ws, size_t ws_size,
                              hipStream_t stream)
{
    const int* x = (const int*)d_in[0];          // (8, 4096) int32
    const float* emb = (const float*)d_in[1];    // (50257, 512) fp32
    float* out = (float*)d_out;                  // (8, 4096, 512) fp32

    const int n_tokens = in_sizes[0];            // 32768
    const int waves_per_block = 256 / 64;        // 4 tokens per block
    const int blocks = (n_tokens + waves_per_block - 1) / waves_per_block;

    embed_gather_kernel<<<blocks, 256, 0, stream>>>(x, emb, out, n_tokens);
}